// Round 6
// baseline (220.391 us; speedup 1.0000x reference)
//
#include <hip/hip_runtime.h>
#include <hip/hip_cooperative_groups.h>
#include <math.h>

namespace cg = cooperative_groups;

// Problem constants
#define PB 2048          // P (sequence length)
// ws layout (float offsets), all [b][chan][p] transposed for coalescing
#define OFF_ENC 0        // enc_t (phi output): [4][32][2048]
#define OFF_Q   262144   // q = psi@V : [4][4][2048]
#define OFF_R   294912   // r = comb@U + c : [4][4][2048]
#define OFF_MSK 327680   // mask: [4][2048]
#define OFF_WV  335872   // wv: [16][33][2048] (scan of w, w*enc)

// ---------------------------------------------------------------------------
// Single cooperative kernel, 256 blocks x 256 threads (1 block/CU):
//  Phase 1 (blocks 0..63): encode. 2 lanes/position (__shfl_xor(.,32)).
//    phi MLP -> enc_t ; psi MLP -> q = psi2@V ; r = comb@U + arho_b@U2
//  grid.sync()
//  Phase 2 (global waves 0..527): per-(bh,c) fused scan+exp+mul+scan -> wv
//  grid.sync()
//  Phase 3 (all blocks, 2 tiles each): out5=C/L -> rho MLP (128->64->64)
__global__ __launch_bounds__(256) void k_fused(
    const float* __restrict__ times, const float* __restrict__ vals,
    const int* __restrict__ meas, const float* __restrict__ mask,
    const float* __restrict__ psi_w1, const float* __restrict__ psi_b1,
    const float* __restrict__ psi_w2, const float* __restrict__ psi_b2,
    const float* __restrict__ phi_w1, const float* __restrict__ phi_b1,
    const float* __restrict__ phi_w2, const float* __restrict__ phi_b2,
    const float* __restrict__ arho_w, const float* __restrict__ arho_b,
    const float* __restrict__ W_k, const float* __restrict__ W_q,
    const float* __restrict__ rho_w1, const float* __restrict__ rho_b1,
    const float* __restrict__ rho_w2, const float* __restrict__ rho_b2,
    float* __restrict__ ws, float* __restrict__ out)
{
    cg::grid_group grid = cg::this_grid();

    // phase-1 LDS
    __shared__ float sW[4222];
    __shared__ float sU[31*4];
    __shared__ float sU2[32*4];
    __shared__ float sV[32*4];
    __shared__ float sCc[4];
    // phase-3 LDS
    __shared__ float h1s[16][65];
    __shared__ float scl[16][4];
    __shared__ float mskS[16];

    const int tid = threadIdx.x;

    // ======================= Phase 1: encode =======================
    if (blockIdx.x < 64) {
        // psi_w1 31x33 [0,1023), psi_b1 [1023,1055), psi_w2 [1055,2079), psi_b2 [2079,2111)
        // phi_w1 31x33 [2111,3134), phi_b1 [3134,3166), phi_w2 [3166,4190), phi_b2 [4190,4222)
        for (int i = tid; i < 1023; i += 256) {
            int r = i / 33, cc = i - r * 33;
            sW[i]        = (cc < 32) ? psi_w1[r*32 + cc] : 0.0f;
            sW[2111 + i] = (cc < 32) ? phi_w1[r*32 + cc] : 0.0f;
        }
        for (int i = tid; i < 1024; i += 256) {
            sW[1055 + i] = psi_w2[i];
            sW[3166 + i] = phi_w2[i];
        }
        if (tid < 32) {
            int i = tid;
            sW[1023 + i] = psi_b1[i];
            sW[2079 + i] = psi_b2[i];
            sW[3134 + i] = phi_b1[i];
            sW[4190 + i] = phi_b2[i];
        }
        for (int t = tid; t < 252; t += 256) {
            int i = t >> 2, h = t & 3;
            float s = 0.0f;
            #pragma unroll
            for (int d = 0; d < 16; d++)
                s = fmaf(W_k[i*64 + d*4 + h], W_q[h*16 + d], s);
            s *= 0.25f;   // 1/sqrt(16)
            if (i < 31) sU[i*4 + h] = s; else sU2[(i-31)*4 + h] = s;
        }
        __syncthreads();
        if (tid < 128) {
            int ch = tid >> 2, h = tid & 3;
            float s = 0.0f;
            #pragma unroll
            for (int j = 0; j < 32; j++)
                s = fmaf(arho_w[ch*32 + j], sU2[j*4 + h], s);
            sV[tid] = s;
        }
        if (tid < 4) {
            float s = 0.0f;
            #pragma unroll
            for (int j = 0; j < 32; j++)
                s = fmaf(arho_b[j], sU2[j*4 + tid], s);
            sCc[tid] = s;
        }
        __syncthreads();

        const int lane = tid & 63;
        const int wave = tid >> 6;
        const int half = lane >> 5;             // 0: j in [0,16), 1: j in [16,32)
        const int jb   = half << 4;
        const int pp = blockIdx.x * 128 + wave * 32 + (lane & 31);
        const int b = pp >> 11, p = pp & 2047;
        const float t = times[pp];
        const float v = vals[pp];
        const float msk = mask[pp];
        const int m = meas[pp];

        float c[9];
        c[0] = sinf(t);           c[1] = cosf(t);
        c[2] = sinf(t * 0.1f);    c[3] = cosf(t * 0.1f);
        c[4] = sinf(t * 0.01f);   c[5] = cosf(t * 0.01f);
        c[6] = sinf(t * 0.001f);  c[7] = cosf(t * 0.001f);
        c[8] = v;

        float* enc_t = ws + OFF_ENC;
        const int cb = b * 32;

        float x[9];
        #pragma unroll
        for (int i = 0; i < 9; i++) x[i] = c[i] * msk;
        const float ohs = (m > 0) ? msk : 0.0f;
        const int   ohr = (m > 0) ? (8 + m) * 33 : 0;

        // ---- r = comb @ U + arho_b@U2 (combined raw/unmasked) ----
        if (half == 0) {
            float r[4] = {sCc[0], sCc[1], sCc[2], sCc[3]};
            #pragma unroll
            for (int i = 0; i < 9; i++) {
                #pragma unroll
                for (int h = 0; h < 4; h++) r[h] = fmaf(c[i], sU[i*4 + h], r[h]);
            }
            if (m > 0) {
                #pragma unroll
                for (int h = 0; h < 4; h++) r[h] += sU[(8 + m)*4 + h];
            }
            #pragma unroll
            for (int h = 0; h < 4; h++)
                ws[OFF_R + (size_t)(b*4 + h) * PB + p] = r[h];
            ws[OFF_MSK + (size_t)b * PB + p] = msk;
        }

        // ---- psi MLP -> q ----
        {
            float h1o[16];
            #pragma unroll
            for (int jj = 0; jj < 16; jj++) {
                const int j = jb + jj;
                float acc = sW[1023 + j];
                #pragma unroll
                for (int i = 0; i < 9; i++) acc = fmaf(x[i], sW[i*33 + j], acc);
                acc = fmaf(ohs, sW[ohr + j], acc);
                h1o[jj] = fmaxf(acc, 0.0f) * msk;
            }
            float h1f[32];
            #pragma unroll
            for (int jj = 0; jj < 16; jj++) {
                const float other = __shfl_xor(h1o[jj], 32);
                h1f[jj]      = half ? other   : h1o[jj];
                h1f[16 + jj] = half ? h1o[jj] : other;
            }
            float q[4] = {0.f, 0.f, 0.f, 0.f};
            #pragma unroll
            for (int jj = 0; jj < 16; jj++) {
                const int j = jb + jj;
                float acc = sW[2079 + j];
                #pragma unroll
                for (int i = 0; i < 32; i++) acc = fmaf(h1f[i], sW[1055 + i*32 + j], acc);
                const float p2 = fmaxf(acc, 0.0f) * msk;
                #pragma unroll
                for (int h = 0; h < 4; h++) q[h] = fmaf(p2, sV[j*4 + h], q[h]);
            }
            #pragma unroll
            for (int h = 0; h < 4; h++) q[h] += __shfl_xor(q[h], 32);
            if (half == 0) {
                #pragma unroll
                for (int h = 0; h < 4; h++)
                    ws[OFF_Q + (size_t)(b*4 + h) * PB + p] = q[h];
            }
        }
        // ---- phi MLP -> enc_t ----
        {
            float h1o[16];
            #pragma unroll
            for (int jj = 0; jj < 16; jj++) {
                const int j = jb + jj;
                float acc = sW[3134 + j];
                #pragma unroll
                for (int i = 0; i < 9; i++) acc = fmaf(x[i], sW[2111 + i*33 + j], acc);
                acc = fmaf(ohs, sW[2111 + ohr + j], acc);
                h1o[jj] = fmaxf(acc, 0.0f) * msk;
            }
            float h1f[32];
            #pragma unroll
            for (int jj = 0; jj < 16; jj++) {
                const float other = __shfl_xor(h1o[jj], 32);
                h1f[jj]      = half ? other   : h1o[jj];
                h1f[16 + jj] = half ? h1o[jj] : other;
            }
            #pragma unroll
            for (int jj = 0; jj < 16; jj++) {
                const int j = jb + jj;
                float acc = sW[4190 + j];
                #pragma unroll
                for (int i = 0; i < 32; i++) acc = fmaf(h1f[i], sW[3166 + i*32 + j], acc);
                enc_t[(size_t)(cb + j) * PB + p] = fmaxf(acc, 0.0f) * msk;
            }
        }
    }

    grid.sync();

    // ======================= Phase 2: mid ==========================
    {
        const int wid = blockIdx.x * 4 + (tid >> 6);
        if (wid < 528) {
            const int bh = wid / 33;
            const int c  = wid - bh * 33;
            const int b  = bh >> 2;
            const int lane = tid & 63;

            const float4* q4 = (const float4*)(ws + OFF_Q   + (size_t)bh * PB + lane * 32);
            const float4* r4 = (const float4*)(ws + OFF_R   + (size_t)bh * PB + lane * 32);
            const float4* m4 = (const float4*)(ws + OFF_MSK + (size_t)b  * PB + lane * 32);
            const float4* e4 = (const float4*)(ws + OFF_ENC + ((size_t)(b*32 + (c-1))) * PB + lane * 32);
            float4* o4 = (float4*)(ws + OFF_WV + ((size_t)(bh*33 + c)) * PB + lane * 32);

            float vq[32];
            #pragma unroll
            for (int k = 0; k < 8; k++) {
                float4 f = q4[k];
                vq[4*k] = f.x; vq[4*k+1] = f.y; vq[4*k+2] = f.z; vq[4*k+3] = f.w;
            }
            #pragma unroll
            for (int j = 1; j < 32; j++) vq[j] += vq[j-1];
            {
                const float tot = vq[31];
                float x = tot;
                #pragma unroll
                for (int off = 1; off < 64; off <<= 1) {
                    float y = __shfl_up(x, off);
                    if (lane >= off) x += y;
                }
                const float excl = x - tot;
                #pragma unroll
                for (int j = 0; j < 32; j++) vq[j] += excl;
            }
            float v[32];
            #pragma unroll
            for (int k = 0; k < 8; k++) {
                const float4 fr = r4[k];
                const float4 fm = m4[k];
                const int p0 = lane * 32 + 4*k;
                v[4*k+0] = expf(fm.x * (fr.x + vq[4*k+0] / (float)(p0 + 1)));
                v[4*k+1] = expf(fm.y * (fr.y + vq[4*k+1] / (float)(p0 + 2)));
                v[4*k+2] = expf(fm.z * (fr.z + vq[4*k+2] / (float)(p0 + 3)));
                v[4*k+3] = expf(fm.w * (fr.w + vq[4*k+3] / (float)(p0 + 4)));
            }
            if (c > 0) {
                #pragma unroll
                for (int k = 0; k < 8; k++) {
                    float4 f = e4[k];
                    v[4*k] *= f.x; v[4*k+1] *= f.y; v[4*k+2] *= f.z; v[4*k+3] *= f.w;
                }
            }
            #pragma unroll
            for (int j = 1; j < 32; j++) v[j] += v[j-1];
            const float tot = v[31];
            float x = tot;
            #pragma unroll
            for (int off = 1; off < 64; off <<= 1) {
                float y = __shfl_up(x, off);
                if (lane >= off) x += y;
            }
            const float excl = x - tot;
            #pragma unroll
            for (int j = 0; j < 32; j++) v[j] += excl;
            #pragma unroll
            for (int k = 0; k < 8; k++)
                o4[k] = make_float4(v[4*k], v[4*k+1], v[4*k+2], v[4*k+3]);
        }
    }

    grid.sync();

    // ======================= Phase 3: rho ==========================
    #pragma unroll 1
    for (int it = 0; it < 2; it++) {
        const int vb = blockIdx.x * 2 + it;     // 0..511
        const int pos = tid >> 4;               // 0..15
        const int g   = tid & 15;               // output group of 4
        const int pbase = vb * 16;
        const int b  = pbase >> 11;
        const int p0 = pbase & 2047;
        const float* wv = ws + OFF_WV + (size_t)b * 132 * PB;

        __syncthreads();   // protect LDS reuse across iterations
        if (tid < 64) {
            const int pp = tid >> 2, h = tid & 3;
            const float msk = ws[OFF_MSK + (size_t)b * PB + p0 + pp];
            const float L = wv[(size_t)(h*33) * PB + p0 + pp];
            scl[pp][h] = msk / L;
            if (h == 0) mskS[pp] = msk;
        }
        __syncthreads();

        const int pg = p0 + pos;
        float4 acc = ((const float4*)rho_b1)[g];
        const float4* w14 = (const float4*)rho_w1;
        const float sc0 = scl[pos][0], sc1 = scl[pos][1];
        const float sc2 = scl[pos][2], sc3 = scl[pos][3];
        #pragma unroll
        for (int h = 0; h < 4; h++) {
            const float sc = (h == 0) ? sc0 : (h == 1) ? sc1 : (h == 2) ? sc2 : sc3;
            const float* wvh = wv + (size_t)(h*33 + 1) * PB + pg;
            #pragma unroll 8
            for (int d = 0; d < 32; d++) {
                const float ai = wvh[(size_t)d * PB] * sc;
                const float4 w = w14[(h*32 + d)*16 + g];
                acc.x = fmaf(ai, w.x, acc.x);
                acc.y = fmaf(ai, w.y, acc.y);
                acc.z = fmaf(ai, w.z, acc.z);
                acc.w = fmaf(ai, w.w, acc.w);
            }
        }
        const float msk = mskS[pos];
        h1s[pos][g*4+0] = fmaxf(acc.x, 0.f) * msk;
        h1s[pos][g*4+1] = fmaxf(acc.y, 0.f) * msk;
        h1s[pos][g*4+2] = fmaxf(acc.z, 0.f) * msk;
        h1s[pos][g*4+3] = fmaxf(acc.w, 0.f) * msk;
        __syncthreads();

        float4 acc2 = ((const float4*)rho_b2)[g];
        const float4* w24 = (const float4*)rho_w2;
        #pragma unroll 16
        for (int i = 0; i < 64; i++) {
            const float hv = h1s[pos][i];
            const float4 w = w24[i*16 + g];
            acc2.x = fmaf(hv, w.x, acc2.x);
            acc2.y = fmaf(hv, w.y, acc2.y);
            acc2.z = fmaf(hv, w.z, acc2.z);
            acc2.w = fmaf(hv, w.w, acc2.w);
        }
        float4 o;
        o.x = fmaxf(acc2.x, 0.f) * msk;
        o.y = fmaxf(acc2.y, 0.f) * msk;
        o.z = fmaxf(acc2.z, 0.f) * msk;
        o.w = fmaxf(acc2.w, 0.f) * msk;
        ((float4*)out)[(size_t)(pbase + pos) * 16 + g] = o;   // lane-contiguous
    }
}

// ---------------------------------------------------------------------------
extern "C" void kernel_launch(void* const* d_in, const int* in_sizes, int n_in,
                              void* d_out, int out_size, void* d_ws, size_t ws_size,
                              hipStream_t stream)
{
    const float* times  = (const float*)d_in[0];
    const float* vals   = (const float*)d_in[1];
    const int*   meas   = (const int*)d_in[2];
    const float* mask   = (const float*)d_in[3];
    const float* psi_w1 = (const float*)d_in[4];
    const float* psi_b1 = (const float*)d_in[5];
    const float* psi_w2 = (const float*)d_in[6];
    const float* psi_b2 = (const float*)d_in[7];
    const float* arho_w = (const float*)d_in[8];
    const float* arho_b = (const float*)d_in[9];
    const float* W_k    = (const float*)d_in[10];
    const float* W_q    = (const float*)d_in[11];
    const float* phi_w1 = (const float*)d_in[12];
    const float* phi_b1 = (const float*)d_in[13];
    const float* phi_w2 = (const float*)d_in[14];
    const float* phi_b2 = (const float*)d_in[15];
    const float* rho_w1 = (const float*)d_in[16];
    const float* rho_b1 = (const float*)d_in[17];
    const float* rho_w2 = (const float*)d_in[18];
    const float* rho_b2 = (const float*)d_in[19];
    float* ws  = (float*)d_ws;
    float* out = (float*)d_out;

    void* args[] = {
        (void*)&times, (void*)&vals, (void*)&meas, (void*)&mask,
        (void*)&psi_w1, (void*)&psi_b1, (void*)&psi_w2, (void*)&psi_b2,
        (void*)&phi_w1, (void*)&phi_b1, (void*)&phi_w2, (void*)&phi_b2,
        (void*)&arho_w, (void*)&arho_b, (void*)&W_k, (void*)&W_q,
        (void*)&rho_w1, (void*)&rho_b1, (void*)&rho_w2, (void*)&rho_b2,
        (void*)&ws, (void*)&out
    };
    hipLaunchCooperativeKernel((const void*)k_fused, dim3(256), dim3(256),
                               args, 0, stream);
}

// Round 7
// 136.717 us; speedup vs baseline: 1.6120x; 1.6120x over previous
//
#include <hip/hip_runtime.h>
#include <math.h>

// Problem constants
#define PB 2048          // P (sequence length)
// ws layout (float offsets), all [b][chan][p] transposed for coalescing
#define OFF_ENC 0        // enc_t (phi output): [4][32][2048]
#define OFF_Q   262144   // q = psi@V : [4][4][2048]
#define OFF_R   294912   // r = comb@U + c : [4][4][2048]
#define OFF_MSK 327680   // mask: [4][2048]
#define OFF_WV  335872   // wv: [16][33][2048] (scan of w, w*enc)

// ---------------------------------------------------------------------------
// K1: per-position encode, 2 lanes per position (halves exchanged via
// __shfl_xor(.,32) -- both halves live in the same wave64).
//   combined(31) -> phi MLP -> enc_t
//   combined(31) -> psi MLP -> q = psi2 @ V   (V = arho_w @ U2, folded here)
//   r = comb @ U[0:31] + arho_b @ U2          (U = fold(W_k,W_q)/sqrt(DOT))
// Linearity: cumsum(psi)@V == cumsum(psi@V), so only 4 scan channels remain.
__global__ __launch_bounds__(64) void k_encode(
    const float* __restrict__ times, const float* __restrict__ vals,
    const int* __restrict__ meas, const float* __restrict__ mask,
    const float* __restrict__ psi_w1, const float* __restrict__ psi_b1,
    const float* __restrict__ psi_w2, const float* __restrict__ psi_b2,
    const float* __restrict__ phi_w1, const float* __restrict__ phi_b1,
    const float* __restrict__ phi_w2, const float* __restrict__ phi_b2,
    const float* __restrict__ arho_w, const float* __restrict__ arho_b,
    const float* __restrict__ W_k, const float* __restrict__ W_q,
    float* __restrict__ ws)
{
    // psi_w1 31x33 [0,1023), psi_b1 [1023,1055), psi_w2 [1055,2079), psi_b2 [2079,2111)
    // phi_w1 31x33 [2111,3134), phi_b1 [3134,3166), phi_w2 [3166,4190), phi_b2 [4190,4222)
    __shared__ float sW[4222];
    __shared__ float sU[31*4];    // combined-part columns of folded key matrix
    __shared__ float sU2[32*4];   // agg-part columns (temp)
    __shared__ float sV[32*4];    // arho_w @ U2
    __shared__ float sCc[4];      // arho_b @ U2
    for (int i = threadIdx.x; i < 1023; i += 64) {
        int r = i / 33, cc = i - r * 33;
        sW[i]        = (cc < 32) ? psi_w1[r*32 + cc] : 0.0f;
        sW[2111 + i] = (cc < 32) ? phi_w1[r*32 + cc] : 0.0f;
    }
    for (int i = threadIdx.x; i < 1024; i += 64) {
        sW[1055 + i] = psi_w2[i];
        sW[3166 + i] = phi_w2[i];
    }
    if (threadIdx.x < 32) {
        int i = threadIdx.x;
        sW[1023 + i] = psi_b1[i];
        sW[2079 + i] = psi_b2[i];
        sW[3134 + i] = phi_b1[i];
        sW[4190 + i] = phi_b2[i];
    }
    for (int t = threadIdx.x; t < 252; t += 64) {
        int i = t >> 2, h = t & 3;
        float s = 0.0f;
        #pragma unroll
        for (int d = 0; d < 16; d++)
            s = fmaf(W_k[i*64 + d*4 + h], W_q[h*16 + d], s);
        s *= 0.25f;   // 1/sqrt(16)
        if (i < 31) sU[i*4 + h] = s; else sU2[(i-31)*4 + h] = s;
    }
    __syncthreads();
    for (int t = threadIdx.x; t < 128; t += 64) {
        int ch = t >> 2, h = t & 3;
        float s = 0.0f;
        #pragma unroll
        for (int j = 0; j < 32; j++)
            s = fmaf(arho_w[ch*32 + j], sU2[j*4 + h], s);
        sV[t] = s;
    }
    if (threadIdx.x < 4) {
        float s = 0.0f;
        #pragma unroll
        for (int j = 0; j < 32; j++)
            s = fmaf(arho_b[j], sU2[j*4 + threadIdx.x], s);
        sCc[threadIdx.x] = s;
    }
    __syncthreads();

    const int tid  = threadIdx.x;
    const int half = tid >> 5;              // 0: j in [0,16), 1: j in [16,32)
    const int jb   = half << 4;             // own output base
    const int pp = blockIdx.x * 32 + (tid & 31);
    const int b = pp >> 11, p = pp & 2047;
    const float t = times[pp];
    const float v = vals[pp];
    const float msk = mask[pp];
    const int m = meas[pp];

    float c[9];
    c[0] = sinf(t);           c[1] = cosf(t);
    c[2] = sinf(t * 0.1f);    c[3] = cosf(t * 0.1f);
    c[4] = sinf(t * 0.01f);   c[5] = cosf(t * 0.01f);
    c[6] = sinf(t * 0.001f);  c[7] = cosf(t * 0.001f);
    c[8] = v;

    float* enc_t = ws + OFF_ENC;
    const int cb = b * 32;

    float x[9];
    #pragma unroll
    for (int i = 0; i < 9; i++) x[i] = c[i] * msk;
    const float ohs = (m > 0) ? msk : 0.0f;
    const int   ohr = (m > 0) ? (8 + m) * 33 : 0;

    // ---- r = comb @ U + arho_b@U2 (combined raw/unmasked, per reference) --
    if (half == 0) {
        float r[4] = {sCc[0], sCc[1], sCc[2], sCc[3]};
        #pragma unroll
        for (int i = 0; i < 9; i++) {
            #pragma unroll
            for (int h = 0; h < 4; h++) r[h] = fmaf(c[i], sU[i*4 + h], r[h]);
        }
        if (m > 0) {
            #pragma unroll
            for (int h = 0; h < 4; h++) r[h] += sU[(8 + m)*4 + h];
        }
        #pragma unroll
        for (int h = 0; h < 4; h++)
            ws[OFF_R + (size_t)(b*4 + h) * PB + p] = r[h];
        ws[OFF_MSK + (size_t)b * PB + p] = msk;
    }

    // ---- psi MLP -> q ----
    {
        float h1o[16];
        #pragma unroll
        for (int jj = 0; jj < 16; jj++) {
            const int j = jb + jj;
            float acc = sW[1023 + j];
            #pragma unroll
            for (int i = 0; i < 9; i++) acc = fmaf(x[i], sW[i*33 + j], acc);
            acc = fmaf(ohs, sW[ohr + j], acc);
            h1o[jj] = fmaxf(acc, 0.0f) * msk;
        }
        float h1f[32];
        #pragma unroll
        for (int jj = 0; jj < 16; jj++) {
            const float other = __shfl_xor(h1o[jj], 32);
            h1f[jj]      = half ? other   : h1o[jj];
            h1f[16 + jj] = half ? h1o[jj] : other;
        }
        float q[4] = {0.f, 0.f, 0.f, 0.f};
        #pragma unroll
        for (int jj = 0; jj < 16; jj++) {
            const int j = jb + jj;
            float acc = sW[2079 + j];
            #pragma unroll
            for (int i = 0; i < 32; i++) acc = fmaf(h1f[i], sW[1055 + i*32 + j], acc);
            const float p2 = fmaxf(acc, 0.0f) * msk;
            #pragma unroll
            for (int h = 0; h < 4; h++) q[h] = fmaf(p2, sV[j*4 + h], q[h]);
        }
        #pragma unroll
        for (int h = 0; h < 4; h++) q[h] += __shfl_xor(q[h], 32);
        if (half == 0) {
            #pragma unroll
            for (int h = 0; h < 4; h++)
                ws[OFF_Q + (size_t)(b*4 + h) * PB + p] = q[h];
        }
    }
    // ---- phi MLP -> enc_t ----
    {
        float h1o[16];
        #pragma unroll
        for (int jj = 0; jj < 16; jj++) {
            const int j = jb + jj;
            float acc = sW[3134 + j];
            #pragma unroll
            for (int i = 0; i < 9; i++) acc = fmaf(x[i], sW[2111 + i*33 + j], acc);
            acc = fmaf(ohs, sW[2111 + ohr + j], acc);
            h1o[jj] = fmaxf(acc, 0.0f) * msk;
        }
        float h1f[32];
        #pragma unroll
        for (int jj = 0; jj < 16; jj++) {
            const float other = __shfl_xor(h1o[jj], 32);
            h1f[jj]      = half ? other   : h1o[jj];
            h1f[16 + jj] = half ? h1o[jj] : other;
        }
        #pragma unroll
        for (int jj = 0; jj < 16; jj++) {
            const int j = jb + jj;
            float acc = sW[4190 + j];
            #pragma unroll
            for (int i = 0; i < 32; i++) acc = fmaf(h1f[i], sW[3166 + i*32 + j], acc);
            enc_t[(size_t)(cb + j) * PB + p] = fmaxf(acc, 0.0f) * msk;
        }
    }
}

// ---------------------------------------------------------------------------
// K2: fused scan+exp+weight-mul+scan. Block = one (bh, c), c in [0,33):
//   cumq = inclusive-scan(q[bh])                       (redundant per c: cheap)
//   ex   = exp(msk * (r[bh] + cumq/(p+1)))
//   v    = (c==0) ? ex : ex * enc[b][c-1]
//   wv[bh][c] = inclusive-scan(v)
__global__ __launch_bounds__(64) void k_mid(float* __restrict__ ws)
{
    const int blk = blockIdx.x;
    const int bh = blk / 33;
    const int c  = blk - bh * 33;
    const int b  = bh >> 2;
    const int lane = threadIdx.x;

    const float4* q4 = (const float4*)(ws + OFF_Q   + (size_t)bh * PB + lane * 32);
    const float4* r4 = (const float4*)(ws + OFF_R   + (size_t)bh * PB + lane * 32);
    const float4* m4 = (const float4*)(ws + OFF_MSK + (size_t)b  * PB + lane * 32);
    const float4* e4 = (const float4*)(ws + OFF_ENC + ((size_t)(b*32 + (c-1))) * PB + lane * 32);
    float4* o4 = (float4*)(ws + OFF_WV + ((size_t)(bh*33 + c)) * PB + lane * 32);

    float vq[32];
    #pragma unroll
    for (int k = 0; k < 8; k++) {
        float4 f = q4[k];
        vq[4*k] = f.x; vq[4*k+1] = f.y; vq[4*k+2] = f.z; vq[4*k+3] = f.w;
    }
    // inclusive scan of q
    #pragma unroll
    for (int j = 1; j < 32; j++) vq[j] += vq[j-1];
    {
        const float tot = vq[31];
        float x = tot;
        #pragma unroll
        for (int off = 1; off < 64; off <<= 1) {
            float y = __shfl_up(x, off);
            if (lane >= off) x += y;
        }
        const float excl = x - tot;
        #pragma unroll
        for (int j = 0; j < 32; j++) vq[j] += excl;
    }
    // ex = exp(msk*(r + cumq/(p+1))), then multiply by enc channel
    float v[32];
    #pragma unroll
    for (int k = 0; k < 8; k++) {
        const float4 fr = r4[k];
        const float4 fm = m4[k];
        const int p0 = lane * 32 + 4*k;
        v[4*k+0] = expf(fm.x * (fr.x + vq[4*k+0] / (float)(p0 + 1)));
        v[4*k+1] = expf(fm.y * (fr.y + vq[4*k+1] / (float)(p0 + 2)));
        v[4*k+2] = expf(fm.z * (fr.z + vq[4*k+2] / (float)(p0 + 3)));
        v[4*k+3] = expf(fm.w * (fr.w + vq[4*k+3] / (float)(p0 + 4)));
    }
    if (c > 0) {
        #pragma unroll
        for (int k = 0; k < 8; k++) {
            float4 f = e4[k];
            v[4*k] *= f.x; v[4*k+1] *= f.y; v[4*k+2] *= f.z; v[4*k+3] *= f.w;
        }
    }
    // inclusive scan of v
    #pragma unroll
    for (int j = 1; j < 32; j++) v[j] += v[j-1];
    const float tot = v[31];
    float x = tot;
    #pragma unroll
    for (int off = 1; off < 64; off <<= 1) {
        float y = __shfl_up(x, off);
        if (lane >= off) x += y;
    }
    const float excl = x - tot;
    #pragma unroll
    for (int j = 0; j < 32; j++) v[j] += excl;
    #pragma unroll
    for (int k = 0; k < 8; k++)
        o4[k] = make_float4(v[4*k], v[4*k+1], v[4*k+2], v[4*k+3]);
}

// ---------------------------------------------------------------------------
// K3: out5 = C/L -> agg2(128) -> rho MLP (128->64->64).
// 512 blocks x 256 threads; block = 16 positions; thread = (pos, 4-output
// group). The 132x16 wv tile is staged through LDS with coalesced float4
// loads (3 VMEM instrs/thread vs 128 near-empty broadcast loads before);
// stride-20 rows keep LDS writes 16B-aligned at worst 2-way bank aliasing
// (free per m136). FMA loop reads tile via LDS broadcast.
__global__ __launch_bounds__(256) void k_rho(
    const float* __restrict__ rho_w1, const float* __restrict__ rho_b1,
    const float* __restrict__ rho_w2, const float* __restrict__ rho_b2,
    const float* __restrict__ ws, float* __restrict__ out)
{
    __shared__ float a2s[132 * 20];  // [chan][pos], stride 20
    __shared__ float h1s[16][65];    // [pos][j]
    __shared__ float mskS[16];
    const int tid = threadIdx.x;
    const int pbase = blockIdx.x * 16;
    const int b  = pbase >> 11;
    const int p0 = pbase & 2047;
    const float* wv = ws + OFF_WV + (size_t)b * 132 * PB;   // 4*33 channels

    // stage 132 channels x 16 positions (rows include the L rows at h*33)
    for (int i = tid; i < 528; i += 256) {
        const int r = i >> 2, q = i & 3;
        const float4 f = *(const float4*)(wv + (size_t)r * PB + p0 + q*4);
        *(float4*)(&a2s[r*20 + q*4]) = f;
    }
    if (tid < 16) mskS[tid] = ws[OFF_MSK + (size_t)b * PB + p0 + tid];
    __syncthreads();

    const int pos = tid >> 4;       // 0..15
    const int g   = tid & 15;       // output group of 4
    const float msk = mskS[pos];

    float4 acc = ((const float4*)rho_b1)[g];
    const float4* w14 = (const float4*)rho_w1;
    #pragma unroll
    for (int h = 0; h < 4; h++) {
        const float sc = msk / a2s[(h*33)*20 + pos];
        #pragma unroll 8
        for (int d = 0; d < 32; d++) {
            const float ai = a2s[(h*33 + 1 + d)*20 + pos] * sc;
            const float4 w = w14[(h*32 + d)*16 + g];
            acc.x = fmaf(ai, w.x, acc.x);
            acc.y = fmaf(ai, w.y, acc.y);
            acc.z = fmaf(ai, w.z, acc.z);
            acc.w = fmaf(ai, w.w, acc.w);
        }
    }
    h1s[pos][g*4+0] = fmaxf(acc.x, 0.f) * msk;
    h1s[pos][g*4+1] = fmaxf(acc.y, 0.f) * msk;
    h1s[pos][g*4+2] = fmaxf(acc.z, 0.f) * msk;
    h1s[pos][g*4+3] = fmaxf(acc.w, 0.f) * msk;
    __syncthreads();

    float4 acc2 = ((const float4*)rho_b2)[g];
    const float4* w24 = (const float4*)rho_w2;
    #pragma unroll 16
    for (int i = 0; i < 64; i++) {
        const float hv = h1s[pos][i];
        const float4 w = w24[i*16 + g];
        acc2.x = fmaf(hv, w.x, acc2.x);
        acc2.y = fmaf(hv, w.y, acc2.y);
        acc2.z = fmaf(hv, w.z, acc2.z);
        acc2.w = fmaf(hv, w.w, acc2.w);
    }
    float4 o;
    o.x = fmaxf(acc2.x, 0.f) * msk;
    o.y = fmaxf(acc2.y, 0.f) * msk;
    o.z = fmaxf(acc2.z, 0.f) * msk;
    o.w = fmaxf(acc2.w, 0.f) * msk;
    ((float4*)out)[(size_t)(pbase + pos) * 16 + g] = o;   // lane-contiguous
}

// ---------------------------------------------------------------------------
extern "C" void kernel_launch(void* const* d_in, const int* in_sizes, int n_in,
                              void* d_out, int out_size, void* d_ws, size_t ws_size,
                              hipStream_t stream)
{
    const float* times  = (const float*)d_in[0];
    const float* vals   = (const float*)d_in[1];
    const int*   meas   = (const int*)d_in[2];
    const float* mask   = (const float*)d_in[3];
    const float* psi_w1 = (const float*)d_in[4];
    const float* psi_b1 = (const float*)d_in[5];
    const float* psi_w2 = (const float*)d_in[6];
    const float* psi_b2 = (const float*)d_in[7];
    const float* arho_w = (const float*)d_in[8];
    const float* arho_b = (const float*)d_in[9];
    const float* W_k    = (const float*)d_in[10];
    const float* W_q    = (const float*)d_in[11];
    const float* phi_w1 = (const float*)d_in[12];
    const float* phi_b1 = (const float*)d_in[13];
    const float* phi_w2 = (const float*)d_in[14];
    const float* phi_b2 = (const float*)d_in[15];
    const float* rho_w1 = (const float*)d_in[16];
    const float* rho_b1 = (const float*)d_in[17];
    const float* rho_w2 = (const float*)d_in[18];
    const float* rho_b2 = (const float*)d_in[19];
    float* ws  = (float*)d_ws;
    float* out = (float*)d_out;

    k_encode<<<dim3(256), dim3(64), 0, stream>>>(times, vals, meas, mask,
        psi_w1, psi_b1, psi_w2, psi_b2, phi_w1, phi_b1, phi_w2, phi_b2,
        arho_w, arho_b, W_k, W_q, ws);
    k_mid<<<dim3(528), dim3(64), 0, stream>>>(ws);
    k_rho<<<dim3(512), dim3(256), 0, stream>>>(rho_w1, rho_b1, rho_w2, rho_b2, ws, out);
}